// Round 4
// baseline (210.271 us; speedup 1.0000x reference)
//
#include <hip/hip_runtime.h>
#include <hip/hip_bf16.h>
#include <hip/hip_fp16.h>

// ============================================================================
// GCN forward. CSR-by-dst via fixed-capacity bucketed counting sort; fused
// gather+dense layer kernels, 8 lanes/node, batched edge-split gathers.
//
// KEY LAYOUT RULE (this round): every randomly-gathered table must fit the
// 4 MB per-XCD L2 (each XCD caches its own copy; 6.4 MB tables thrash -> L3
// round-trips, measured 54.7 MB FETCH_SIZE on a 6.4 MB table).
//   - xs   -> xsA [n][16 fp16] (3.2MB) + xsB [n][2 fp16] (0.4MB)
//   - h2s  -> h2sA/h2sB [n][16 fp16] (3.2MB each); layer3 split into two
//     sequential kernels (pass A gathers only h2sA, pass B only h2sB) so only
//     one 3.2MB table is random-hot chip-wide at a time; pass A's partial
//     dense output (16 f's) round-trips via pl3 [n][16 fp16].
//   - h3s [n][16] (3.2MB), h4s [n][2] (0.4MB) already fit.
//   - gather: 4 edges per loop iteration, out-of-range slots clamp to a
//     dedicated all-zero row at index n (tables have n+1 rows).
//   - dense: packed-fp16 weights in LDS + v_dot2_f32_f16 (f32 accumulate).
// Algebra: A_hat(xW) = (A_hat x)W, normalization factored as
//   out[d] = dinv[d] * ( sum_{s in N(d)} hs[s] + hs[d] ) + b,  hs = h*dinv[row]
// ============================================================================

#define NBUCK_SHIFT 8            // 256 nodes per bucket
#define CAP         8192         // bucket capacity (avg 4096, sigma ~64)
#define PART_CHUNK  2048         // edges per partition block (256 thr x 8)

// ---------------- fp16 pair helpers ----------------
typedef _Float16 h2vec __attribute__((ext_vector_type(2)));

__device__ inline unsigned int pack2(float a, float b) {
    __half2 h = __floats2half2_rn(a, b);
    return *reinterpret_cast<unsigned int*>(&h);
}

__device__ inline float2 h2f(unsigned int u) {
    __half2 h = *reinterpret_cast<__half2*>(&u);
    return __half22float2(h);
}

__device__ inline float dot2f(unsigned int w, unsigned int h, float c) {
#if defined(__has_builtin) && __has_builtin(__builtin_amdgcn_fdot2)
    union U { unsigned int u; h2vec v; };
    U uw, uh; uw.u = w; uh.u = h;
    return __builtin_amdgcn_fdot2(uh.v, uw.v, c, false);
#else
    float2 wf = h2f(w);
    float2 hf = h2f(h);
    return fmaf(hf.x, wf.x, fmaf(hf.y, wf.y, c));
#endif
}

// accumulate 8 halves (one uint4) into acc[0..7]
__device__ inline void accq(float* acc, const uint4& r) {
    float2 t;
    t = h2f(r.x); acc[0] += t.x; acc[1] += t.y;
    t = h2f(r.y); acc[2] += t.x; acc[3] += t.y;
    t = h2f(r.z); acc[4] += t.x; acc[5] += t.y;
    t = h2f(r.w); acc[6] += t.x; acc[7] += t.y;
}

// ---------------- init per-bucket cursors to fixed bases ----------------
__global__ void init_gcur_kernel(int* __restrict__ gcur, int nbuck) {
    int i = threadIdx.x;
    if (i < nbuck) gcur[i] = i * CAP;
}

// ---------------- partition edges into fixed-capacity buckets ----------------
// staged word: (src << 8) | (dst & 255)
__global__ __launch_bounds__(256) void partition_kernel(const int* __restrict__ src,
                                                        const int* __restrict__ dst,
                                                        int* __restrict__ gcur,
                                                        unsigned int* __restrict__ bucketed,
                                                        int n_edges, int nbuck) {
    __shared__ int cnt[512];
    __shared__ int base[512];
    const int t = threadIdx.x;
    for (int i = t; i < 512; i += 256) cnt[i] = 0;
    __syncthreads();
    long long start = (long long)blockIdx.x * PART_CHUNK;
    int sv[8], dv[8], bv[8];
#pragma unroll
    for (int k = 0; k < 8; ++k) {
        long long e = start + (long long)k * 256 + t;
        bool ok = e < n_edges;
        sv[k] = ok ? src[e] : 0;
        dv[k] = ok ? dst[e] : 0;
        bv[k] = ok ? (dv[k] >> NBUCK_SHIFT) : -1;
        if (ok) atomicAdd(&cnt[bv[k]], 1);
    }
    __syncthreads();
    for (int i = t; i < nbuck; i += 256) {
        int c = cnt[i];
        base[i] = c ? atomicAdd(&gcur[i], c) : 0;
    }
    __syncthreads();
    for (int i = t; i < 512; i += 256) cnt[i] = 0;   // reuse as running cursor
    __syncthreads();
#pragma unroll
    for (int k = 0; k < 8; ++k) {
        if (bv[k] >= 0) {
            int pos = base[bv[k]] + atomicAdd(&cnt[bv[k]], 1);
            bucketed[pos] = ((unsigned int)sv[k] << 8) | (unsigned int)(dv[k] & 255);
        }
    }
}

// ---------------- per-bucket CSR finalize + x scale/pack ---------------------
__device__ inline float4 pack8_dev(const float* v) {
    float4 out;
    __half2* h2 = reinterpret_cast<__half2*>(&out);
#pragma unroll
    for (int j = 0; j < 4; ++j) h2[j] = __floats2half2_rn(v[2 * j], v[2 * j + 1]);
    return out;
}

__global__ __launch_bounds__(256) void csr_kernel(const unsigned int* __restrict__ bucketed,
                                                  const int* __restrict__ gcur,
                                                  const float* __restrict__ x,
                                                  int2* __restrict__ ends,
                                                  float* __restrict__ dinv,
                                                  int* __restrict__ sorted_src,
                                                  __half* __restrict__ xsA,
                                                  __half* __restrict__ xsB,
                                                  int n) {
    __shared__ int ldeg[256];
    __shared__ int lscan[256];
    const int b = blockIdx.x;
    const int t = threadIdx.x;
    const int beg = b * CAP;
    const int end = gcur[b];                 // beg + count(bucket b)
    ldeg[t] = 0;
    __syncthreads();
    for (int e = beg + t; e < end; e += 256) {
        unsigned int p = bucketed[e];
        atomicAdd(&ldeg[p & 255u], 1);
    }
    __syncthreads();
    int v = ldeg[t];
    lscan[t] = v;
    __syncthreads();
    for (int off = 1; off < 256; off <<= 1) {
        int xv = (t >= off) ? lscan[t - off] : 0;
        __syncthreads();
        lscan[t] += xv;
        __syncthreads();
    }
    int excl = lscan[t] - v;                 // exclusive scan
    int node = (b << NBUCK_SHIFT) + t;
    float di = rsqrtf((float)v + 1.0f);      // +1 self-loop
    if (node < n) {
        ends[node] = make_int2(beg + excl, beg + excl + v);
        dinv[node] = di;
        const float* xr = x + (long long)node * 18;
        float vv[18];
#pragma unroll
        for (int k = 0; k < 18; ++k) vv[k] = xr[k] * di;
        float4* oa = reinterpret_cast<float4*>(xsA + (long long)node * 16);
        oa[0] = pack8_dev(vv);
        oa[1] = pack8_dev(vv + 8);
        *reinterpret_cast<__half2*>(xsB + (long long)node * 2) =
            __floats2half2_rn(vv[16], vv[17]);
    }
    if (b == 0 && t == 0) {                  // dummy zero rows at index n
        float4 z = make_float4(0.0f, 0.0f, 0.0f, 0.0f);
        float4* oa = reinterpret_cast<float4*>(xsA + (long long)n * 16);
        oa[0] = z; oa[1] = z;
        *reinterpret_cast<__half2*>(xsB + (long long)n * 2) = __floats2half2_rn(0.0f, 0.0f);
    }
    __syncthreads();
    lscan[t] = beg + excl;                   // reuse as placement cursor
    __syncthreads();
    for (int e = beg + t; e < end; e += 256) {
        unsigned int p = bucketed[e];
        int pos = atomicAdd(&lscan[p & 255u], 1);
        sorted_src[pos] = (int)(p >> 8);
    }
}

// ---------------- fused layer 1+2 (8 lanes/node, batched edge-split) --------
__global__ __launch_bounds__(256) void layer12_kernel(
    const __half* __restrict__ xsA, const __half* __restrict__ xsB,
    const float* __restrict__ dinv,
    const int* __restrict__ sorted_src, const int2* __restrict__ ends,
    const float* __restrict__ W1, const float* __restrict__ b1,
    const float* __restrict__ W2,
    __half* __restrict__ h2sA, __half* __restrict__ h2sB, int n) {
    __shared__ unsigned int w1h[9 * 64];     // [kp][j] pairs of x-dim
    __shared__ float sB1[64];
    __shared__ unsigned int w2h[32 * 32];    // [jp][f] pairs of hidden-dim
    for (int i = threadIdx.x; i < 9 * 64; i += 256) {
        int kp = i >> 6, j = i & 63;
        w1h[i] = pack2(W1[(2 * kp) * 64 + j], W1[(2 * kp + 1) * 64 + j]);
    }
    for (int i = threadIdx.x; i < 64; i += 256) sB1[i] = b1[i];
    for (int i = threadIdx.x; i < 32 * 32; i += 256) {
        int jp = i >> 5, f = i & 31;
        w2h[i] = pack2(W2[(2 * jp) * 32 + f], W2[(2 * jp + 1) * 32 + f]);
    }
    __syncthreads();

    long long gt = (long long)blockIdx.x * 256 + threadIdx.x;
    int node = (int)(gt >> 3);
    int l8   = (int)(gt & 7);
    if (node >= n) return;
    int2 be = ends[node];
    float di = dinv[node];

    // ---- gather: 4-way batched edge-split; dummy slots -> zero row n ----
    float acc[18];
#pragma unroll
    for (int j = 0; j < 18; ++j) acc[j] = 0.0f;
    if (l8 == 7) {   // self row
        const __half* pa = xsA + ((long long)node << 4);
        uint4 ra = *reinterpret_cast<const uint4*>(pa);
        uint4 rb = *reinterpret_cast<const uint4*>(pa + 8);
        unsigned int rc = *reinterpret_cast<const unsigned int*>(xsB + ((long long)node << 1));
        accq(acc, ra); accq(acc + 8, rb);
        float2 t = h2f(rc); acc[16] += t.x; acc[17] += t.y;
    }
    const int last = be.y - 1;
    for (int e = be.x + l8; e < be.y; e += 32) {
        int i1 = e + 8, i2 = e + 16, i3 = e + 24;
        int s0 = sorted_src[e];
        int v1 = sorted_src[i1 <= last ? i1 : last];
        int v2 = sorted_src[i2 <= last ? i2 : last];
        int v3 = sorted_src[i3 <= last ? i3 : last];
        int s1 = (i1 <= last) ? v1 : n;
        int s2 = (i2 <= last) ? v2 : n;
        int s3 = (i3 <= last) ? v3 : n;
        const __half* p0 = xsA + ((long long)s0 << 4);
        const __half* p1 = xsA + ((long long)s1 << 4);
        const __half* p2 = xsA + ((long long)s2 << 4);
        const __half* p3 = xsA + ((long long)s3 << 4);
        uint4 r0a = *reinterpret_cast<const uint4*>(p0);
        uint4 r0b = *reinterpret_cast<const uint4*>(p0 + 8);
        unsigned int r0c = *reinterpret_cast<const unsigned int*>(xsB + ((long long)s0 << 1));
        uint4 r1a = *reinterpret_cast<const uint4*>(p1);
        uint4 r1b = *reinterpret_cast<const uint4*>(p1 + 8);
        unsigned int r1c = *reinterpret_cast<const unsigned int*>(xsB + ((long long)s1 << 1));
        uint4 r2a = *reinterpret_cast<const uint4*>(p2);
        uint4 r2b = *reinterpret_cast<const uint4*>(p2 + 8);
        unsigned int r2c = *reinterpret_cast<const unsigned int*>(xsB + ((long long)s2 << 1));
        uint4 r3a = *reinterpret_cast<const uint4*>(p3);
        uint4 r3b = *reinterpret_cast<const uint4*>(p3 + 8);
        unsigned int r3c = *reinterpret_cast<const unsigned int*>(xsB + ((long long)s3 << 1));
        float2 t;
        accq(acc, r0a); accq(acc + 8, r0b); t = h2f(r0c); acc[16] += t.x; acc[17] += t.y;
        accq(acc, r1a); accq(acc + 8, r1b); t = h2f(r1c); acc[16] += t.x; acc[17] += t.y;
        accq(acc, r2a); accq(acc + 8, r2b); t = h2f(r2c); acc[16] += t.x; acc[17] += t.y;
        accq(acc, r3a); accq(acc + 8, r3b); t = h2f(r3c); acc[16] += t.x; acc[17] += t.y;
    }
#pragma unroll
    for (int j = 0; j < 18; ++j) {       // all-reduce over octet (di folded later)
        acc[j] += __shfl_xor(acc[j], 1);
        acc[j] += __shfl_xor(acc[j], 2);
        acc[j] += __shfl_xor(acc[j], 4);
    }
    unsigned int ap[9];
#pragma unroll
    for (int q = 0; q < 9; ++q) ap[q] = pack2(acc[2 * q], acc[2 * q + 1]);

    // ---- stage 1: hidden slice j0 = l8*8, dot2 over 9 k-pairs ----
    const int j0 = l8 * 8;
    float raw[8];
#pragma unroll
    for (int jj = 0; jj < 8; ++jj) raw[jj] = 0.0f;
#pragma unroll
    for (int kp = 0; kp < 9; ++kp) {
        const uint4* wv = reinterpret_cast<const uint4*>(&w1h[kp * 64 + j0]);
        uint4 wa = wv[0], wb = wv[1];
        unsigned int a = ap[kp];
        raw[0] = dot2f(wa.x, a, raw[0]); raw[1] = dot2f(wa.y, a, raw[1]);
        raw[2] = dot2f(wa.z, a, raw[2]); raw[3] = dot2f(wa.w, a, raw[3]);
        raw[4] = dot2f(wb.x, a, raw[4]); raw[5] = dot2f(wb.y, a, raw[5]);
        raw[6] = dot2f(wb.z, a, raw[6]); raw[7] = dot2f(wb.w, a, raw[7]);
    }
    unsigned int hpu[4];
#pragma unroll
    for (int q = 0; q < 4; ++q) {          // hid = relu(di*raw + b1), packed
        float h0 = fmaxf(fmaf(raw[2 * q],     di, sB1[j0 + 2 * q]),     0.0f);
        float h1 = fmaxf(fmaf(raw[2 * q + 1], di, sB1[j0 + 2 * q + 1]), 0.0f);
        hpu[q] = pack2(h0, h1);
    }

    // ---- stage 2: f-split (f0 = l8*4); hid pairs exchanged via octet shfl --
    float out[4] = {0.0f, 0.0f, 0.0f, 0.0f};
#pragma unroll
    for (int m = 0; m < 8; ++m) {
        const int lx = l8 ^ m;
#pragma unroll
        for (int q = 0; q < 4; ++q) {
            unsigned int hh = m ? (unsigned int)__shfl_xor(hpu[q], m) : hpu[q];
            const uint4 w = *reinterpret_cast<const uint4*>(&w2h[(lx * 4 + q) * 32 + l8 * 4]);
            out[0] = dot2f(w.x, hh, out[0]);
            out[1] = dot2f(w.y, hh, out[1]);
            out[2] = dot2f(w.z, hh, out[2]);
            out[3] = dot2f(w.w, hh, out[3]);
        }
    }
    union { float2 f2; __half2 h2[2]; } u;
    u.h2[0] = __floats2half2_rn(out[0] * di, out[1] * di);
    u.h2[1] = __floats2half2_rn(out[2] * di, out[3] * di);
    // dims [4*l8, 4*l8+4): lanes 0-3 -> h2sA, lanes 4-7 -> h2sB
    __half* hb = (l8 < 4) ? h2sA : h2sB;
    *reinterpret_cast<float2*>(hb + (long long)node * 16 + 4 * (l8 & 3)) = u.f2;
    if (node == 0)                           // dummy zero rows at index n
        *reinterpret_cast<float2*>(hb + (long long)n * 16 + 4 * (l8 & 3)) =
            make_float2(0.0f, 0.0f);
}

// ---------------- layer 3 pass A: gather h2sA (k=0..15) -> partial ----------
__global__ __launch_bounds__(256) void layer3a_kernel(
    const __half* __restrict__ h2sA, const float* __restrict__ dinv,
    const int* __restrict__ sorted_src, const int2* __restrict__ ends,
    const float* __restrict__ b2, const float* __restrict__ W3,
    __half* __restrict__ pl3, int n) {
    __shared__ unsigned int w3h[8 * 16];     // [kp][f], k-pairs 0..7 (k=0..15)
    __shared__ float sB[16];
    {
        int i = threadIdx.x;
        if (i < 128) {
            int kp = i >> 4, f = i & 15;
            w3h[i] = pack2(W3[(2 * kp) * 16 + f], W3[(2 * kp + 1) * 16 + f]);
        }
        if (i < 16) sB[i] = b2[i];
    }
    __syncthreads();

    long long gt = (long long)blockIdx.x * 256 + threadIdx.x;
    int node = (int)(gt >> 3);
    int l8   = (int)(gt & 7);
    if (node >= n) return;
    int2 be = ends[node];
    float di = dinv[node];

    float acc[16];
#pragma unroll
    for (int j = 0; j < 16; ++j) acc[j] = 0.0f;
    if (l8 == 7) {
        const uint4* pp = reinterpret_cast<const uint4*>(h2sA + ((long long)node << 4));
        accq(acc, pp[0]); accq(acc + 8, pp[1]);
    }
    const int last = be.y - 1;
    for (int e = be.x + l8; e < be.y; e += 32) {
        int i1 = e + 8, i2 = e + 16, i3 = e + 24;
        int s0 = sorted_src[e];
        int v1 = sorted_src[i1 <= last ? i1 : last];
        int v2 = sorted_src[i2 <= last ? i2 : last];
        int v3 = sorted_src[i3 <= last ? i3 : last];
        int s1 = (i1 <= last) ? v1 : n;
        int s2 = (i2 <= last) ? v2 : n;
        int s3 = (i3 <= last) ? v3 : n;
        const uint4* p0 = reinterpret_cast<const uint4*>(h2sA + ((long long)s0 << 4));
        const uint4* p1 = reinterpret_cast<const uint4*>(h2sA + ((long long)s1 << 4));
        const uint4* p2 = reinterpret_cast<const uint4*>(h2sA + ((long long)s2 << 4));
        const uint4* p3 = reinterpret_cast<const uint4*>(h2sA + ((long long)s3 << 4));
        uint4 r00 = p0[0], r01 = p0[1];
        uint4 r10 = p1[0], r11 = p1[1];
        uint4 r20 = p2[0], r21 = p2[1];
        uint4 r30 = p3[0], r31 = p3[1];
        accq(acc, r00); accq(acc + 8, r01);
        accq(acc, r10); accq(acc + 8, r11);
        accq(acc, r20); accq(acc + 8, r21);
        accq(acc, r30); accq(acc + 8, r31);
    }
    // reduce-scatter acc[16] over octet -> lane owns k in [2*l8, 2*l8+2)
    const bool hi4 = (l8 & 4);
    float h8[8];
#pragma unroll
    for (int v = 0; v < 8; ++v) {
        float keep = hi4 ? acc[8 + v] : acc[v];
        float send = hi4 ? acc[v] : acc[8 + v];
        h8[v] = keep + __shfl_xor(send, 4);
    }
    const bool hi2 = (l8 & 2);
    float h4v[4];
#pragma unroll
    for (int v = 0; v < 4; ++v) {
        float keep = hi2 ? h8[4 + v] : h8[v];
        float send = hi2 ? h8[v] : h8[4 + v];
        h4v[v] = keep + __shfl_xor(send, 2);
    }
    const bool hi1 = (l8 & 1);
    float k2[2];
#pragma unroll
    for (int v = 0; v < 2; ++v) {
        float keep = hi1 ? h4v[2 + v] : h4v[v];
        float send = hi1 ? h4v[v] : h4v[2 + v];
        k2[v] = keep + __shfl_xor(send, 1);
    }
    const int k0 = l8 * 2;
    float v0 = fmaxf(fmaf(k2[0], di, sB[k0 + 0]), 0.0f);
    float v1 = fmaxf(fmaf(k2[1], di, sB[k0 + 1]), 0.0f);
    unsigned int vp = pack2(v0, v1);
    float o0 = 0.0f, o1 = 0.0f;
#pragma unroll
    for (int m = 0; m < 8; ++m) {
        unsigned int hh = m ? (unsigned int)__shfl_xor(vp, m) : vp;
        const uint2 w = *reinterpret_cast<const uint2*>(&w3h[(l8 ^ m) * 16 + k0]);
        o0 = dot2f(w.x, hh, o0);
        o1 = dot2f(w.y, hh, o1);
    }
    *reinterpret_cast<__half2*>(pl3 + (long long)node * 16 + k0) =
        __floats2half2_rn(o0, o1);
}

// ---------------- layer 3 pass B: gather h2sB (k=16..31) + partial -> h3s ---
__global__ __launch_bounds__(256) void layer3b_kernel(
    const __half* __restrict__ h2sB, const float* __restrict__ dinv,
    const int* __restrict__ sorted_src, const int2* __restrict__ ends,
    const float* __restrict__ b2, const float* __restrict__ W3,
    const __half* __restrict__ pl3, __half* __restrict__ h3s, int n) {
    __shared__ unsigned int w3h[8 * 16];     // [kp][f], k-pairs 8..15 (k=16..31)
    __shared__ float sB[16];
    {
        int i = threadIdx.x;
        if (i < 128) {
            int kp = i >> 4, f = i & 15;
            w3h[i] = pack2(W3[(16 + 2 * kp) * 16 + f], W3[(17 + 2 * kp) * 16 + f]);
        }
        if (i < 16) sB[i] = b2[16 + i];
    }
    __syncthreads();

    long long gt = (long long)blockIdx.x * 256 + threadIdx.x;
    int node = (int)(gt >> 3);
    int l8   = (int)(gt & 7);
    if (node >= n) return;
    int2 be = ends[node];
    float di = dinv[node];

    float acc[16];
#pragma unroll
    for (int j = 0; j < 16; ++j) acc[j] = 0.0f;
    if (l8 == 7) {
        const uint4* pp = reinterpret_cast<const uint4*>(h2sB + ((long long)node << 4));
        accq(acc, pp[0]); accq(acc + 8, pp[1]);
    }
    const int last = be.y - 1;
    for (int e = be.x + l8; e < be.y; e += 32) {
        int i1 = e + 8, i2 = e + 16, i3 = e + 24;
        int s0 = sorted_src[e];
        int v1 = sorted_src[i1 <= last ? i1 : last];
        int v2 = sorted_src[i2 <= last ? i2 : last];
        int v3 = sorted_src[i3 <= last ? i3 : last];
        int s1 = (i1 <= last) ? v1 : n;
        int s2 = (i2 <= last) ? v2 : n;
        int s3 = (i3 <= last) ? v3 : n;
        const uint4* p0 = reinterpret_cast<const uint4*>(h2sB + ((long long)s0 << 4));
        const uint4* p1 = reinterpret_cast<const uint4*>(h2sB + ((long long)s1 << 4));
        const uint4* p2 = reinterpret_cast<const uint4*>(h2sB + ((long long)s2 << 4));
        const uint4* p3 = reinterpret_cast<const uint4*>(h2sB + ((long long)s3 << 4));
        uint4 r00 = p0[0], r01 = p0[1];
        uint4 r10 = p1[0], r11 = p1[1];
        uint4 r20 = p2[0], r21 = p2[1];
        uint4 r30 = p3[0], r31 = p3[1];
        accq(acc, r00); accq(acc + 8, r01);
        accq(acc, r10); accq(acc + 8, r11);
        accq(acc, r20); accq(acc + 8, r21);
        accq(acc, r30); accq(acc + 8, r31);
    }
    // reduce-scatter acc[16] over octet -> lane owns k in [2*l8, 2*l8+2)
    const bool hi4 = (l8 & 4);
    float h8[8];
#pragma unroll
    for (int v = 0; v < 8; ++v) {
        float keep = hi4 ? acc[8 + v] : acc[v];
        float send = hi4 ? acc[v] : acc[8 + v];
        h8[v] = keep + __shfl_xor(send, 4);
    }
    const bool hi2 = (l8 & 2);
    float h4v[4];
#pragma unroll
    for (int v = 0; v < 4; ++v) {
        float keep = hi2 ? h8[4 + v] : h8[v];
        float send = hi2 ? h8[v] : h8[4 + v];
        h4v[v] = keep + __shfl_xor(send, 2);
    }
    const bool hi1 = (l8 & 1);
    float k2[2];
#pragma unroll
    for (int v = 0; v < 2; ++v) {
        float keep = hi1 ? h4v[2 + v] : h4v[v];
        float send = hi1 ? h4v[v] : h4v[2 + v];
        k2[v] = keep + __shfl_xor(send, 1);
    }
    const int k0 = l8 * 2;
    float v0 = fmaxf(fmaf(k2[0], di, sB[k0 + 0]), 0.0f);
    float v1 = fmaxf(fmaf(k2[1], di, sB[k0 + 1]), 0.0f);
    unsigned int vp = pack2(v0, v1);
    float o0 = 0.0f, o1 = 0.0f;
#pragma unroll
    for (int m = 0; m < 8; ++m) {
        unsigned int hh = m ? (unsigned int)__shfl_xor(vp, m) : vp;
        const uint2 w = *reinterpret_cast<const uint2*>(&w3h[(l8 ^ m) * 16 + k0]);
        o0 = dot2f(w.x, hh, o0);
        o1 = dot2f(w.y, hh, o1);
    }
    float2 pp = __half22float2(*reinterpret_cast<const __half2*>(pl3 + (long long)node * 16 + k0));
    *reinterpret_cast<__half2*>(h3s + (long long)node * 16 + k0) =
        __floats2half2_rn((pp.x + o0) * di, (pp.y + o1) * di);
    if (node == 0)                           // dummy zero row h3s[n]
        *reinterpret_cast<__half2*>(h3s + (long long)n * 16 + k0) =
            __floats2half2_rn(0.0f, 0.0f);
}

// ---------------- fused layer 4 (8 lanes/node, batched edge-split) -----------
__global__ __launch_bounds__(256) void layer4_kernel(
    const __half* __restrict__ h3s, const float* __restrict__ dinv,
    const int* __restrict__ sorted_src, const int2* __restrict__ ends,
    const float* __restrict__ b3, const float* __restrict__ W4,
    __half* __restrict__ h4s, int n) {
    __shared__ float sW4[32];
    __shared__ float sB3[16];
    for (int i = threadIdx.x; i < 32; i += 256) sW4[i] = W4[i];
    for (int i = threadIdx.x; i < 16; i += 256) sB3[i] = b3[i];
    __syncthreads();

    long long gt = (long long)blockIdx.x * 256 + threadIdx.x;
    int node = (int)(gt >> 3);
    int l8   = (int)(gt & 7);
    if (node >= n) return;
    int2 be = ends[node];
    float di = dinv[node];

    float acc[16];
#pragma unroll
    for (int j = 0; j < 16; ++j) acc[j] = 0.0f;
    if (l8 == 7) {
        const uint4* pp = reinterpret_cast<const uint4*>(h3s + ((long long)node << 4));
        accq(acc, pp[0]); accq(acc + 8, pp[1]);
    }
    const int last = be.y - 1;
    for (int e = be.x + l8; e < be.y; e += 32) {
        int i1 = e + 8, i2 = e + 16, i3 = e + 24;
        int s0 = sorted_src[e];
        int v1 = sorted_src[i1 <= last ? i1 : last];
        int v2 = sorted_src[i2 <= last ? i2 : last];
        int v3 = sorted_src[i3 <= last ? i3 : last];
        int s1 = (i1 <= last) ? v1 : n;
        int s2 = (i2 <= last) ? v2 : n;
        int s3 = (i3 <= last) ? v3 : n;
        const uint4* p0 = reinterpret_cast<const uint4*>(h3s + ((long long)s0 << 4));
        const uint4* p1 = reinterpret_cast<const uint4*>(h3s + ((long long)s1 << 4));
        const uint4* p2 = reinterpret_cast<const uint4*>(h3s + ((long long)s2 << 4));
        const uint4* p3 = reinterpret_cast<const uint4*>(h3s + ((long long)s3 << 4));
        uint4 r00 = p0[0], r01 = p0[1];
        uint4 r10 = p1[0], r11 = p1[1];
        uint4 r20 = p2[0], r21 = p2[1];
        uint4 r30 = p3[0], r31 = p3[1];
        accq(acc, r00); accq(acc + 8, r01);
        accq(acc, r10); accq(acc + 8, r11);
        accq(acc, r20); accq(acc + 8, r21);
        accq(acc, r30); accq(acc + 8, r31);
    }
    // reduce-scatter acc[16] over octet -> lane owns k in [2*l8, 2*l8+2)
    const bool hi4 = (l8 & 4);
    float h8[8];
#pragma unroll
    for (int v = 0; v < 8; ++v) {
        float keep = hi4 ? acc[8 + v] : acc[v];
        float send = hi4 ? acc[v] : acc[8 + v];
        h8[v] = keep + __shfl_xor(send, 4);
    }
    const bool hi2 = (l8 & 2);
    float h4v[4];
#pragma unroll
    for (int v = 0; v < 4; ++v) {
        float keep = hi2 ? h8[4 + v] : h8[v];
        float send = hi2 ? h8[v] : h8[4 + v];
        h4v[v] = keep + __shfl_xor(send, 2);
    }
    const bool hi1 = (l8 & 1);
    float k2[2];
#pragma unroll
    for (int v = 0; v < 2; ++v) {
        float keep = hi1 ? h4v[2 + v] : h4v[v];
        float send = hi1 ? h4v[v] : h4v[2 + v];
        k2[v] = keep + __shfl_xor(send, 1);
    }
    const int k0 = l8 * 2;
    float o0 = 0.0f, o1 = 0.0f;
#pragma unroll
    for (int kk = 0; kk < 2; ++kk) {
        float v = fmaxf(fmaf(k2[kk], di, sB3[k0 + kk]), 0.0f);
        o0 = fmaf(v, sW4[2 * (k0 + kk)], o0);
        o1 = fmaf(v, sW4[2 * (k0 + kk) + 1], o1);
    }
    o0 += __shfl_xor(o0, 1); o0 += __shfl_xor(o0, 2); o0 += __shfl_xor(o0, 4);
    o1 += __shfl_xor(o1, 1); o1 += __shfl_xor(o1, 2); o1 += __shfl_xor(o1, 4);
    if (l8 == 0) {
        *reinterpret_cast<__half2*>(h4s + 2LL * node) = __floats2half2_rn(o0 * di, o1 * di);
        if (node == 0)                       // dummy zero row h4s[n]
            *reinterpret_cast<__half2*>(h4s + 2LL * n) = __floats2half2_rn(0.0f, 0.0f);
    }
}

// ---------------- final: F=2 aggregation + log_softmax (8 lanes/node) --------
__global__ __launch_bounds__(256) void agg2_lsm_kernel(
    const __half* __restrict__ hs, const float* __restrict__ dinv,
    const int* __restrict__ sorted_src, const int2* __restrict__ ends,
    const float* __restrict__ b, float* __restrict__ out, int n) {
    long long gt = (long long)blockIdx.x * 256 + threadIdx.x;
    int node = (int)(gt >> 3);
    int l8   = (int)(gt & 7);
    if (node >= n) return;
    int2 be = ends[node];
    float ax = 0.0f, ay = 0.0f;
    if (l8 == 7) {
        float2 r = __half22float2(*reinterpret_cast<const __half2*>(hs + 2LL * node));
        ax += r.x; ay += r.y;
    }
    const int last = be.y - 1;
    for (int e = be.x + l8; e < be.y; e += 32) {
        int i1 = e + 8, i2 = e + 16, i3 = e + 24;
        int s0 = sorted_src[e];
        int v1 = sorted_src[i1 <= last ? i1 : last];
        int v2 = sorted_src[i2 <= last ? i2 : last];
        int v3 = sorted_src[i3 <= last ? i3 : last];
        int s1 = (i1 <= last) ? v1 : n;
        int s2 = (i2 <= last) ? v2 : n;
        int s3 = (i3 <= last) ? v3 : n;
        unsigned int r0 = *reinterpret_cast<const unsigned int*>(hs + 2LL * s0);
        unsigned int r1 = *reinterpret_cast<const unsigned int*>(hs + 2LL * s1);
        unsigned int r2 = *reinterpret_cast<const unsigned int*>(hs + 2LL * s2);
        unsigned int r3 = *reinterpret_cast<const unsigned int*>(hs + 2LL * s3);
        float2 t;
        t = h2f(r0); ax += t.x; ay += t.y;
        t = h2f(r1); ax += t.x; ay += t.y;
        t = h2f(r2); ax += t.x; ay += t.y;
        t = h2f(r3); ax += t.x; ay += t.y;
    }
    ax += __shfl_xor(ax, 1); ax += __shfl_xor(ax, 2); ax += __shfl_xor(ax, 4);
    ay += __shfl_xor(ay, 1); ay += __shfl_xor(ay, 2); ay += __shfl_xor(ay, 4);
    if (l8 == 0) {
        float di = dinv[node];
        float a = ax * di + b[0];
        float c = ay * di + b[1];
        float m = fmaxf(a, c);
        float lse = m + logf(expf(a - m) + expf(c - m));
        float2 r = make_float2(a - lse, c - lse);
        *reinterpret_cast<float2*>(out + 2LL * node) = r;
    }
}

static inline int cdiv_ll(long long a, int b) { return (int)((a + b - 1) / b); }
static inline char* align16(char* p) { return (char*)(((uintptr_t)p + 15) & ~(uintptr_t)15); }

extern "C" void kernel_launch(void* const* d_in, const int* in_sizes, int n_in,
                              void* d_out, int out_size, void* d_ws, size_t ws_size,
                              hipStream_t stream) {
    (void)n_in; (void)out_size; (void)ws_size;

    const float* x  = (const float*)d_in[0];      // [N,18]
    const int*   ei = (const int*)d_in[1];        // [2,E]
    const float* W1 = (const float*)d_in[2];
    const float* b1 = (const float*)d_in[3];
    const float* W2 = (const float*)d_in[4];
    const float* b2 = (const float*)d_in[5];
    const float* W3 = (const float*)d_in[6];
    const float* b3 = (const float*)d_in[7];
    const float* W4 = (const float*)d_in[8];
    const float* b4 = (const float*)d_in[9];

    const int n = in_sizes[0] / 18;               // 100000
    const int E = in_sizes[1] / 2;                // 1600000
    const int* src = ei;
    const int* dst = ei + E;
    const int nbuck = (n + 255) >> NBUCK_SHIFT;   // 391

    // ---- workspace layout (16B-aligned; gathered tables have n+1 rows and
    //      each fits the 4MB per-XCD L2) ----
    char* p = (char*)d_ws;
    int*    gcur       = (int*)p;            p = align16(p + 512 * 4);
    int2*   ends       = (int2*)p;           p = align16(p + (size_t)n * 8);
    float*  dinv       = (float*)p;          p = align16(p + (size_t)n * 4);
    int*    sorted_src = (int*)p;            p = align16(p + (size_t)nbuck * CAP * 4);  // 12.8MB padded
    unsigned int* bucketed = (unsigned int*)p; p = align16(p + (size_t)nbuck * CAP * 4); // 12.8MB padded
    __half* xsA        = (__half*)p;         p = align16(p + (size_t)(n + 1) * 16 * 2); // 3.2MB
    __half* xsB        = (__half*)p;         p = align16(p + (size_t)(n + 1) * 2 * 2);  // 0.4MB
    __half* h2sA       = (__half*)p;         p = align16(p + (size_t)(n + 1) * 16 * 2); // 3.2MB
    __half* h2sB       = (__half*)p;         p = align16(p + (size_t)(n + 1) * 16 * 2); // 3.2MB
    __half* pl3        = (__half*)p;         p = align16(p + (size_t)n * 16 * 2);       // 3.2MB
    __half* h3s        = (__half*)p;         p = align16(p + (size_t)(n + 1) * 16 * 2); // 3.2MB
    __half* h4s        = (__half*)p;         p = align16(p + (size_t)(n + 1) * 2 * 2);  // 0.4MB

    const int B = 256;
    const int NODE8_BLOCKS = cdiv_ll(8LL * n, B);

    // ---- CSR-by-dst via fixed-capacity bucketed sort (no hist/scan) ----
    init_gcur_kernel<<<1, 512, 0, stream>>>(gcur, nbuck);
    partition_kernel<<<cdiv_ll(E, PART_CHUNK), B, 0, stream>>>(src, dst, gcur, bucketed, E, nbuck);
    csr_kernel<<<nbuck, B, 0, stream>>>(bucketed, gcur, x, ends, dinv, sorted_src, xsA, xsB, n);

    // ---- fused pipeline (8 lanes/node, L2-resident gather tables) ----
    layer12_kernel<<<NODE8_BLOCKS, B, 0, stream>>>(xsA, xsB, dinv, sorted_src, ends, W1, b1, W2, h2sA, h2sB, n);
    layer3a_kernel<<<NODE8_BLOCKS, B, 0, stream>>>(h2sA, dinv, sorted_src, ends, b2, W3, pl3, n);
    layer3b_kernel<<<NODE8_BLOCKS, B, 0, stream>>>(h2sB, dinv, sorted_src, ends, b2, W3, pl3, h3s, n);
    layer4_kernel<<<NODE8_BLOCKS, B, 0, stream>>>(h3s, dinv, sorted_src, ends, b3, W4, h4s, n);
    agg2_lsm_kernel<<<NODE8_BLOCKS, B, 0, stream>>>(h4s, dinv, sorted_src, ends, b4, (float*)d_out, n);
}

// Round 6
// 197.170 us; speedup vs baseline: 1.0664x; 1.0664x over previous
//
#include <hip/hip_runtime.h>
#include <hip/hip_bf16.h>
#include <hip/hip_fp16.h>

// ============================================================================
// GCN forward. CSR-by-dst via fixed-capacity bucketed counting sort; fused
// gather+dense layer kernels, 8 lanes/node.
//
// Gather model (validated R0-R3): phases are bound by scattered VMEM
// lane-address throughput/latency. Keep per-edge address count at the floor
// (L12: 3, L3: 4, L4: 2, agg: 1) and maximize concurrency:
//   - L3: 16B-SLICE x EDGE-PARITY split: lane l8 -> slice (l8>>1) of the 64B
//     row, edge parity (l8&1). Same address count, acc[32]->acc[8], 3-stage
//     reduce-scatter -> 1 shfl, VGPR ~40 -> 8 blocks/CU pinned.
//   - L4: 16B-slice x 4-way edge split, acc[16]->acc[8], 2-shfl merge.
//   - L12: edge-split, 2-edge batch (staging halved), (256,6).
//   - out-of-range batch slots clamp to all-zero row at index n.
//   - dense stages: packed-fp16 weights in LDS + v_dot2_f32_f16.
// Algebra: A_hat(xW) = (A_hat x)W; per-edge gather dims 18+32+16+2 (min side).
//   out[d] = dinv[d] * ( sum_{s in N(d)} hs[s] + hs[d] ) + b,  hs = h*dinv[row]
// ============================================================================

#define NBUCK_SHIFT 8            // 256 nodes per bucket
#define CAP         8192         // bucket capacity (avg 4096, sigma ~64)
#define PART_CHUNK  2048         // edges per partition block (256 thr x 8)

// ---------------- fp16 pair helpers ----------------
typedef _Float16 h2vec __attribute__((ext_vector_type(2)));

__device__ inline unsigned int pack2(float a, float b) {
    __half2 h = __floats2half2_rn(a, b);
    return *reinterpret_cast<unsigned int*>(&h);
}

__device__ inline float2 h2f(unsigned int u) {
    __half2 h = *reinterpret_cast<__half2*>(&u);
    return __half22float2(h);
}

__device__ inline float dot2f(unsigned int w, unsigned int h, float c) {
#if defined(__has_builtin) && __has_builtin(__builtin_amdgcn_fdot2)
    union U { unsigned int u; h2vec v; };
    U uw, uh; uw.u = w; uh.u = h;
    return __builtin_amdgcn_fdot2(uh.v, uw.v, c, false);
#else
    float2 wf = h2f(w);
    float2 hf = h2f(h);
    return fmaf(hf.x, wf.x, fmaf(hf.y, wf.y, c));
#endif
}

// accumulate 8 halves (one uint4) into acc[0..7]
__device__ inline void accq(float* acc, const uint4& r) {
    float2 t;
    t = h2f(r.x); acc[0] += t.x; acc[1] += t.y;
    t = h2f(r.y); acc[2] += t.x; acc[3] += t.y;
    t = h2f(r.z); acc[4] += t.x; acc[5] += t.y;
    t = h2f(r.w); acc[6] += t.x; acc[7] += t.y;
}

// ---------------- init per-bucket cursors to fixed bases ----------------
__global__ void init_gcur_kernel(int* __restrict__ gcur, int nbuck) {
    int i = threadIdx.x;
    if (i < nbuck) gcur[i] = i * CAP;
}

// ---------------- partition edges into fixed-capacity buckets ----------------
// staged word: (src << 8) | (dst & 255)
__global__ __launch_bounds__(256) void partition_kernel(const int* __restrict__ src,
                                                        const int* __restrict__ dst,
                                                        int* __restrict__ gcur,
                                                        unsigned int* __restrict__ bucketed,
                                                        int n_edges, int nbuck) {
    __shared__ int cnt[512];
    __shared__ int base[512];
    const int t = threadIdx.x;
    for (int i = t; i < 512; i += 256) cnt[i] = 0;
    __syncthreads();
    long long start = (long long)blockIdx.x * PART_CHUNK;
    int sv[8], dv[8], bv[8];
#pragma unroll
    for (int k = 0; k < 8; ++k) {
        long long e = start + (long long)k * 256 + t;
        bool ok = e < n_edges;
        sv[k] = ok ? src[e] : 0;
        dv[k] = ok ? dst[e] : 0;
        bv[k] = ok ? (dv[k] >> NBUCK_SHIFT) : -1;
        if (ok) atomicAdd(&cnt[bv[k]], 1);
    }
    __syncthreads();
    for (int i = t; i < nbuck; i += 256) {
        int c = cnt[i];
        base[i] = c ? atomicAdd(&gcur[i], c) : 0;
    }
    __syncthreads();
    for (int i = t; i < 512; i += 256) cnt[i] = 0;   // reuse as running cursor
    __syncthreads();
#pragma unroll
    for (int k = 0; k < 8; ++k) {
        if (bv[k] >= 0) {
            int pos = base[bv[k]] + atomicAdd(&cnt[bv[k]], 1);
            bucketed[pos] = ((unsigned int)sv[k] << 8) | (unsigned int)(dv[k] & 255);
        }
    }
}

// ---------------- per-bucket CSR finalize + x scale/pad ----------------------
__device__ inline float4 pack8_dev(const float* v) {
    float4 out;
    __half2* h2 = reinterpret_cast<__half2*>(&out);
#pragma unroll
    for (int j = 0; j < 4; ++j) h2[j] = __floats2half2_rn(v[2 * j], v[2 * j + 1]);
    return out;
}

__global__ __launch_bounds__(256) void csr_kernel(const unsigned int* __restrict__ bucketed,
                                                  const int* __restrict__ gcur,
                                                  const float* __restrict__ x,
                                                  int2* __restrict__ ends,
                                                  float* __restrict__ dinv,
                                                  int* __restrict__ sorted_src,
                                                  __half* __restrict__ xs,
                                                  int n) {
    __shared__ int ldeg[256];
    __shared__ int lscan[256];
    const int b = blockIdx.x;
    const int t = threadIdx.x;
    const int beg = b * CAP;
    const int end = gcur[b];                 // beg + count(bucket b)
    ldeg[t] = 0;
    __syncthreads();
    for (int e = beg + t; e < end; e += 256) {
        unsigned int p = bucketed[e];
        atomicAdd(&ldeg[p & 255u], 1);
    }
    __syncthreads();
    int v = ldeg[t];
    lscan[t] = v;
    __syncthreads();
    for (int off = 1; off < 256; off <<= 1) {
        int xv = (t >= off) ? lscan[t - off] : 0;
        __syncthreads();
        lscan[t] += xv;
        __syncthreads();
    }
    int excl = lscan[t] - v;                 // exclusive scan
    int node = (b << NBUCK_SHIFT) + t;
    float di = rsqrtf((float)v + 1.0f);      // +1 self-loop
    if (node < n) {
        ends[node] = make_int2(beg + excl, beg + excl + v);
        dinv[node] = di;
        // xs row = half(x * di), stride 32 halves, halves 18..31 zeroed
        const float* xr = x + (long long)node * 18;
        float vv[18];
#pragma unroll
        for (int k = 0; k < 18; ++k) vv[k] = xr[k] * di;
        float vt[8] = {vv[16], vv[17], 0.0f, 0.0f, 0.0f, 0.0f, 0.0f, 0.0f};
        float4* o = reinterpret_cast<float4*>(xs + (long long)node * 32);
        o[0] = pack8_dev(vv);
        o[1] = pack8_dev(vv + 8);
        o[2] = pack8_dev(vt);
        o[3] = make_float4(0.0f, 0.0f, 0.0f, 0.0f);
    }
    if (b == 0 && t == 0) {                  // dummy zero row xs[n]
        float4 z = make_float4(0.0f, 0.0f, 0.0f, 0.0f);
        float4* o = reinterpret_cast<float4*>(xs + (long long)n * 32);
        o[0] = z; o[1] = z; o[2] = z; o[3] = z;
    }
    __syncthreads();
    lscan[t] = beg + excl;                   // reuse as placement cursor
    __syncthreads();
    for (int e = beg + t; e < end; e += 256) {
        unsigned int p = bucketed[e];
        int pos = atomicAdd(&lscan[p & 255u], 1);
        sorted_src[pos] = (int)(p >> 8);
    }
}

// ---------------- fused layer 1+2 (8 lanes/node, 2-edge-batch edge-split) ---
__global__ __launch_bounds__(256, 6) void layer12_kernel(
    const __half* __restrict__ xs, const float* __restrict__ dinv,
    const int* __restrict__ sorted_src, const int2* __restrict__ ends,
    const float* __restrict__ W1, const float* __restrict__ b1,
    const float* __restrict__ W2, __half* __restrict__ h2s, int n) {
    __shared__ unsigned int w1h[9 * 64];     // [kp][j] pairs of x-dim
    __shared__ float sB1[64];
    __shared__ unsigned int w2h[32 * 32];    // [jp][f] pairs of hidden-dim
    for (int i = threadIdx.x; i < 9 * 64; i += 256) {
        int kp = i >> 6, j = i & 63;
        w1h[i] = pack2(W1[(2 * kp) * 64 + j], W1[(2 * kp + 1) * 64 + j]);
    }
    for (int i = threadIdx.x; i < 64; i += 256) sB1[i] = b1[i];
    for (int i = threadIdx.x; i < 32 * 32; i += 256) {
        int jp = i >> 5, f = i & 31;
        w2h[i] = pack2(W2[(2 * jp) * 32 + f], W2[(2 * jp + 1) * 32 + f]);
    }
    __syncthreads();

    long long gt = (long long)blockIdx.x * 256 + threadIdx.x;
    int node = (int)(gt >> 3);
    int l8   = (int)(gt & 7);
    if (node >= n) return;
    int2 be = ends[node];
    float di = dinv[node];

    // ---- gather: 2-edge-batched edge-split; dummy slots -> zero row n ----
    float acc[18];
#pragma unroll
    for (int j = 0; j < 18; ++j) acc[j] = 0.0f;
    if (l8 == 7) {   // self row
        const __half* p = xs + ((long long)node << 5);
        uint4 ra = *reinterpret_cast<const uint4*>(p);
        uint4 rb = *reinterpret_cast<const uint4*>(p + 8);
        unsigned int rc = *reinterpret_cast<const unsigned int*>(p + 16);
        accq(acc, ra); accq(acc + 8, rb);
        float2 t = h2f(rc); acc[16] += t.x; acc[17] += t.y;
    }
    const int last = be.y - 1;
    for (int e = be.x + l8; e < be.y; e += 16) {
        int i1 = e + 8;
        int s0 = sorted_src[e];
        int v1 = sorted_src[i1 <= last ? i1 : last];
        int s1 = (i1 <= last) ? v1 : n;
        const __half* p0 = xs + ((long long)s0 << 5);
        const __half* p1 = xs + ((long long)s1 << 5);
        uint4 r0a = *reinterpret_cast<const uint4*>(p0);
        uint4 r0b = *reinterpret_cast<const uint4*>(p0 + 8);
        unsigned int r0c = *reinterpret_cast<const unsigned int*>(p0 + 16);
        uint4 r1a = *reinterpret_cast<const uint4*>(p1);
        uint4 r1b = *reinterpret_cast<const uint4*>(p1 + 8);
        unsigned int r1c = *reinterpret_cast<const unsigned int*>(p1 + 16);
        float2 t;
        accq(acc, r0a); accq(acc + 8, r0b); t = h2f(r0c); acc[16] += t.x; acc[17] += t.y;
        accq(acc, r1a); accq(acc + 8, r1b); t = h2f(r1c); acc[16] += t.x; acc[17] += t.y;
    }
#pragma unroll
    for (int j = 0; j < 18; ++j) {       // all-reduce over octet (di folded later)
        acc[j] += __shfl_xor(acc[j], 1);
        acc[j] += __shfl_xor(acc[j], 2);
        acc[j] += __shfl_xor(acc[j], 4);
    }
    unsigned int ap[9];
#pragma unroll
    for (int q = 0; q < 9; ++q) ap[q] = pack2(acc[2 * q], acc[2 * q + 1]);

    // ---- stage 1: hidden slice j0 = l8*8, dot2 over 9 k-pairs ----
    const int j0 = l8 * 8;
    float raw[8];
#pragma unroll
    for (int jj = 0; jj < 8; ++jj) raw[jj] = 0.0f;
#pragma unroll
    for (int kp = 0; kp < 9; ++kp) {
        const uint4* wv = reinterpret_cast<const uint4*>(&w1h[kp * 64 + j0]);
        uint4 wa = wv[0], wb = wv[1];
        unsigned int a = ap[kp];
        raw[0] = dot2f(wa.x, a, raw[0]); raw[1] = dot2f(wa.y, a, raw[1]);
        raw[2] = dot2f(wa.z, a, raw[2]); raw[3] = dot2f(wa.w, a, raw[3]);
        raw[4] = dot2f(wb.x, a, raw[4]); raw[5] = dot2f(wb.y, a, raw[5]);
        raw[6] = dot2f(wb.z, a, raw[6]); raw[7] = dot2f(wb.w, a, raw[7]);
    }
    unsigned int hpu[4];
#pragma unroll
    for (int q = 0; q < 4; ++q) {          // hid = relu(di*raw + b1), packed
        float h0 = fmaxf(fmaf(raw[2 * q],     di, sB1[j0 + 2 * q]),     0.0f);
        float h1 = fmaxf(fmaf(raw[2 * q + 1], di, sB1[j0 + 2 * q + 1]), 0.0f);
        hpu[q] = pack2(h0, h1);
    }

    // ---- stage 2: f-split (f0 = l8*4); hid pairs exchanged via octet shfl --
    float out[4] = {0.0f, 0.0f, 0.0f, 0.0f};
#pragma unroll
    for (int m = 0; m < 8; ++m) {
        const int lx = l8 ^ m;
#pragma unroll
        for (int q = 0; q < 4; ++q) {
            unsigned int hh = m ? (unsigned int)__shfl_xor(hpu[q], m) : hpu[q];
            const uint4 w = *reinterpret_cast<const uint4*>(&w2h[(lx * 4 + q) * 32 + l8 * 4]);
            out[0] = dot2f(w.x, hh, out[0]);
            out[1] = dot2f(w.y, hh, out[1]);
            out[2] = dot2f(w.z, hh, out[2]);
            out[3] = dot2f(w.w, hh, out[3]);
        }
    }
    union { float2 f2; __half2 h2[2]; } u;
    u.h2[0] = __floats2half2_rn(out[0] * di, out[1] * di);
    u.h2[1] = __floats2half2_rn(out[2] * di, out[3] * di);
    *reinterpret_cast<float2*>(h2s + (long long)node * 32 + l8 * 4) = u.f2;
    if (node == 0)                           // dummy zero row h2s[n]
        *reinterpret_cast<float2*>(h2s + (long long)n * 32 + l8 * 4) = make_float2(0.0f, 0.0f);
}

// ---------------- fused layer 3 (16B-slice x edge-parity gather) ------------
// lane l8: slice s=l8>>1 (dims [8s,8s+8) of the 64B row), edge parity q=l8&1.
// 4 edges per iteration; parity merge = ONE shfl stage; lane then owns
// k in [4*l8, 4*l8+4) directly. Same per-edge address count as edge-split.
__global__ __launch_bounds__(256, 8) void layer3_kernel(
    const __half* __restrict__ h2s, const float* __restrict__ dinv,
    const int* __restrict__ sorted_src, const int2* __restrict__ ends,
    const float* __restrict__ b2, const float* __restrict__ W3,
    __half* __restrict__ h3s, int n) {
    __shared__ unsigned int w3h[16 * 16];    // [kp][f] pairs of k-dim
    __shared__ float sB2[32];
    {
        int i = threadIdx.x;
        if (i < 256) {
            int kp = i >> 4, f = i & 15;
            w3h[i] = pack2(W3[(2 * kp) * 16 + f], W3[(2 * kp + 1) * 16 + f]);
        }
    }
    for (int i = threadIdx.x; i < 32; i += 256) sB2[i] = b2[i];
    __syncthreads();

    long long gt = (long long)blockIdx.x * 256 + threadIdx.x;
    int node = (int)(gt >> 3);
    int l8   = (int)(gt & 7);
    if (node >= n) return;
    int2 be = ends[node];
    float di = dinv[node];
    const int sl = l8 >> 1;                  // 16B slice index
    const int q  = l8 & 1;                   // edge parity
    const long long soff = 8LL * sl;         // slice offset in halves

    float acc[8];
#pragma unroll
    for (int j = 0; j < 8; ++j) acc[j] = 0.0f;
    if (q == 0) {                            // self row, slice sl
        uint4 r = *reinterpret_cast<const uint4*>(h2s + ((long long)node << 5) + soff);
        accq(acc, r);
    }
    const int last = be.y - 1;
    for (int e = be.x + q; e < be.y; e += 8) {
        int i1 = e + 2, i2 = e + 4, i3 = e + 6;
        int s0 = sorted_src[e];
        int v1 = sorted_src[i1 <= last ? i1 : last];
        int v2 = sorted_src[i2 <= last ? i2 : last];
        int v3 = sorted_src[i3 <= last ? i3 : last];
        int s1 = (i1 <= last) ? v1 : n;
        int s2 = (i2 <= last) ? v2 : n;
        int s3 = (i3 <= last) ? v3 : n;
        uint4 r0 = *reinterpret_cast<const uint4*>(h2s + ((long long)s0 << 5) + soff);
        uint4 r1 = *reinterpret_cast<const uint4*>(h2s + ((long long)s1 << 5) + soff);
        uint4 r2 = *reinterpret_cast<const uint4*>(h2s + ((long long)s2 << 5) + soff);
        uint4 r3 = *reinterpret_cast<const uint4*>(h2s + ((long long)s3 << 5) + soff);
        accq(acc, r0); accq(acc, r1); accq(acc, r2); accq(acc, r3);
    }
    // parity merge: one shfl stage; lane now has full sums for dims [8sl,8sl+8)
#pragma unroll
    for (int j = 0; j < 8; ++j) acc[j] += __shfl_xor(acc[j], 1);
    // lane's k-range [4*l8, 4*l8+4) = local [4q, 4q+4)
    float a0 = q ? acc[4] : acc[0];
    float a1 = q ? acc[5] : acc[1];
    float a2 = q ? acc[6] : acc[2];
    float a3 = q ? acc[7] : acc[3];

    // ---- dense: relu'd k-pairs exchanged via octet shfl, dot2 ----
    const int k0 = l8 * 4;
    float v0 = fmaxf(fmaf(a0, di, sB2[k0 + 0]), 0.0f);
    float v1 = fmaxf(fmaf(a1, di, sB2[k0 + 1]), 0.0f);
    float v2 = fmaxf(fmaf(a2, di, sB2[k0 + 2]), 0.0f);
    float v3 = fmaxf(fmaf(a3, di, sB2[k0 + 3]), 0.0f);
    unsigned int vp[2] = { pack2(v0, v1), pack2(v2, v3) };
    float o0 = 0.0f, o1 = 0.0f;
#pragma unroll
    for (int m = 0; m < 8; ++m) {
        const int lx = l8 ^ m;
#pragma unroll
        for (int qq = 0; qq < 2; ++qq) {
            unsigned int hh = m ? (unsigned int)__shfl_xor(vp[qq], m) : vp[qq];
            const uint2 w = *reinterpret_cast<const uint2*>(&w3h[(lx * 2 + qq) * 16 + l8 * 2]);
            o0 = dot2f(w.x, hh, o0);
            o1 = dot2f(w.y, hh, o1);
        }
    }
    *reinterpret_cast<__half2*>(h3s + (long long)node * 16 + l8 * 2) =
        __floats2half2_rn(o0 * di, o1 * di);
    if (node == 0)                           // dummy zero row h3s[n]
        *reinterpret_cast<__half2*>(h3s + (long long)n * 16 + l8 * 2) =
            __floats2half2_rn(0.0f, 0.0f);
}

// ---------------- fused layer 4 (16B-slice x 4-way edge split) --------------
// lane l8: slice s=l8>>2 (dims [8s,8s+8) of the 32B row), edge class q4=l8&3.
// 2-stage shfl merge; lane then owns k in [2*l8, 2*l8+2) directly.
__global__ __launch_bounds__(256, 8) void layer4_kernel(
    const __half* __restrict__ h3s, const float* __restrict__ dinv,
    const int* __restrict__ sorted_src, const int2* __restrict__ ends,
    const float* __restrict__ b3, const float* __restrict__ W4,
    __half* __restrict__ h4s, int n) {
    __shared__ float sW4[32];
    __shared__ float sB3[16];
    for (int i = threadIdx.x; i < 32; i += 256) sW4[i] = W4[i];
    for (int i = threadIdx.x; i < 16; i += 256) sB3[i] = b3[i];
    __syncthreads();

    long long gt = (long long)blockIdx.x * 256 + threadIdx.x;
    int node = (int)(gt >> 3);
    int l8   = (int)(gt & 7);
    if (node >= n) return;
    int2 be = ends[node];
    float di = dinv[node];
    const int sl = l8 >> 2;                  // 16B slice index (0/1)
    const int q4 = l8 & 3;                   // edge class
    const long long soff = 8LL * sl;         // slice offset in halves

    float acc[8];
#pragma unroll
    for (int j = 0; j < 8; ++j) acc[j] = 0.0f;
    if (q4 == 0) {                           // self row, slice sl
        uint4 r = *reinterpret_cast<const uint4*>(h3s + ((long long)node << 4) + soff);
        accq(acc, r);
    }
    const int last = be.y - 1;
    for (int e = be.x + q4; e < be.y; e += 16) {
        int i1 = e + 4, i2 = e + 8, i3 = e + 12;
        int s0 = sorted_src[e];
        int v1 = sorted_src[i1 <= last ? i1 : last];
        int v2 = sorted_src[i2 <= last ? i2 : last];
        int v3 = sorted_src[i3 <= last ? i3 : last];
        int s1 = (i1 <= last) ? v1 : n;
        int s2 = (i2 <= last) ? v2 : n;
        int s3 = (i3 <= last) ? v3 : n;
        uint4 r0 = *reinterpret_cast<const uint4*>(h3s + ((long long)s0 << 4) + soff);
        uint4 r1 = *reinterpret_cast<const uint4*>(h3s + ((long long)s1 << 4) + soff);
        uint4 r2 = *reinterpret_cast<const uint4*>(h3s + ((long long)s2 << 4) + soff);
        uint4 r3 = *reinterpret_cast<const uint4*>(h3s + ((long long)s3 << 4) + soff);
        accq(acc, r0); accq(acc, r1); accq(acc, r2); accq(acc, r3);
    }
    // merge across the 4 edge classes (lanes sharing slice sl)
#pragma unroll
    for (int j = 0; j < 8; ++j) {
        acc[j] += __shfl_xor(acc[j], 1);
        acc[j] += __shfl_xor(acc[j], 2);
    }
    // lane's k-range [2*l8, 2*l8+2) = local [2*q4, 2*q4+2)
    float k20 = (q4 & 2) ? ((q4 & 1) ? acc[6] : acc[4]) : ((q4 & 1) ? acc[2] : acc[0]);
    float k21 = (q4 & 2) ? ((q4 & 1) ? acc[7] : acc[5]) : ((q4 & 1) ? acc[3] : acc[1]);

    const int k0 = l8 * 2;
    float w0a = sW4[2 * k0],       w0b = sW4[2 * k0 + 1];
    float w1a = sW4[2 * (k0 + 1)], w1b = sW4[2 * (k0 + 1) + 1];
    float va = fmaxf(fmaf(k20, di, sB3[k0]),     0.0f);
    float vb = fmaxf(fmaf(k21, di, sB3[k0 + 1]), 0.0f);
    float o0 = fmaf(va, w0a, vb * w1a);
    float o1 = fmaf(va, w0b, vb * w1b);
    o0 += __shfl_xor(o0, 1); o0 += __shfl_xor(o0, 2); o0 += __shfl_xor(o0, 4);
    o1 += __shfl_xor(o1, 1); o1 += __shfl_xor(o1, 2); o1 += __shfl_xor(o1, 4);
    if (l8 == 0) {
        *reinterpret_cast<__half2*>(h4s + 2LL * node) = __floats2half2_rn(o0 * di, o1 * di);
        if (node == 0)                       // dummy zero row h4s[n]
            *reinterpret_cast<__half2*>(h4s + 2LL * n) = __floats2half2_rn(0.0f, 0.0f);
    }
}

// ---------------- final: F=2 aggregation + log_softmax (8 lanes/node) --------
__global__ __launch_bounds__(256, 8) void agg2_lsm_kernel(
    const __half* __restrict__ hs, const float* __restrict__ dinv,
    const int* __restrict__ sorted_src, const int2* __restrict__ ends,
    const float* __restrict__ b, float* __restrict__ out, int n) {
    long long gt = (long long)blockIdx.x * 256 + threadIdx.x;
    int node = (int)(gt >> 3);
    int l8   = (int)(gt & 7);
    if (node >= n) return;
    int2 be = ends[node];
    float ax = 0.0f, ay = 0.0f;
    if (l8 == 7) {
        float2 r = __half22float2(*reinterpret_cast<const __half2*>(hs + 2LL * node));
        ax += r.x; ay += r.y;
    }
    const int last = be.y - 1;
    for (int e = be.x + l8; e < be.y; e += 32) {
        int i1 = e + 8, i2 = e + 16, i3 = e + 24;
        int s0 = sorted_src[e];
        int v1 = sorted_src[i1 <= last ? i1 : last];
        int v2 = sorted_src[i2 <= last ? i2 : last];
        int v3 = sorted_src[i3 <= last ? i3 : last];
        int s1 = (i1 <= last) ? v1 : n;
        int s2 = (i2 <= last) ? v2 : n;
        int s3 = (i3 <= last) ? v3 : n;
        unsigned int r0 = *reinterpret_cast<const unsigned int*>(hs + 2LL * s0);
        unsigned int r1 = *reinterpret_cast<const unsigned int*>(hs + 2LL * s1);
        unsigned int r2 = *reinterpret_cast<const unsigned int*>(hs + 2LL * s2);
        unsigned int r3 = *reinterpret_cast<const unsigned int*>(hs + 2LL * s3);
        float2 t;
        t = h2f(r0); ax += t.x; ay += t.y;
        t = h2f(r1); ax += t.x; ay += t.y;
        t = h2f(r2); ax += t.x; ay += t.y;
        t = h2f(r3); ax += t.x; ay += t.y;
    }
    ax += __shfl_xor(ax, 1); ax += __shfl_xor(ax, 2); ax += __shfl_xor(ax, 4);
    ay += __shfl_xor(ay, 1); ay += __shfl_xor(ay, 2); ay += __shfl_xor(ay, 4);
    if (l8 == 0) {
        float di = dinv[node];
        float a = ax * di + b[0];
        float c = ay * di + b[1];
        float m = fmaxf(a, c);
        float lse = m + logf(expf(a - m) + expf(c - m));
        float2 r = make_float2(a - lse, c - lse);
        *reinterpret_cast<float2*>(out + 2LL * node) = r;
    }
}

static inline int cdiv_ll(long long a, int b) { return (int)((a + b - 1) / b); }
static inline char* align16(char* p) { return (char*)(((uintptr_t)p + 15) & ~(uintptr_t)15); }

extern "C" void kernel_launch(void* const* d_in, const int* in_sizes, int n_in,
                              void* d_out, int out_size, void* d_ws, size_t ws_size,
                              hipStream_t stream) {
    (void)n_in; (void)out_size; (void)ws_size;

    const float* x  = (const float*)d_in[0];      // [N,18]
    const int*   ei = (const int*)d_in[1];        // [2,E]
    const float* W1 = (const float*)d_in[2];
    const float* b1 = (const float*)d_in[3];
    const float* W2 = (const float*)d_in[4];
    const float* b2 = (const float*)d_in[5];
    const float* W3 = (const float*)d_in[6];
    const float* b3 = (const float*)d_in[7];
    const float* W4 = (const float*)d_in[8];
    const float* b4 = (const float*)d_in[9];

    const int n = in_sizes[0] / 18;               // 100000
    const int E = in_sizes[1] / 2;                // 1600000
    const int* src = ei;
    const int* dst = ei + E;
    const int nbuck = (n + 255) >> NBUCK_SHIFT;   // 391

    // ---- workspace layout (16B-aligned; hs tables have n+1 rows) ----
    char* p = (char*)d_ws;
    int*    gcur       = (int*)p;            p = align16(p + 512 * 4);
    int2*   ends       = (int2*)p;           p = align16(p + (size_t)n * 8);
    float*  dinv       = (float*)p;          p = align16(p + (size_t)n * 4);
    int*    sorted_src = (int*)p;            p = align16(p + (size_t)nbuck * CAP * 4);  // 12.8MB padded
    unsigned int* bucketed = (unsigned int*)p; p = align16(p + (size_t)nbuck * CAP * 4); // 12.8MB padded
    __half* xs         = (__half*)p;         p = align16(p + (size_t)(n + 1) * 32 * 2);  // 6.4MB
    __half* h2s        = (__half*)p;         p = align16(p + (size_t)(n + 1) * 32 * 2);  // 6.4MB
    __half* h3s        = (__half*)p;         p = align16(p + (size_t)(n + 1) * 16 * 2);  // 3.2MB
    __half* h4s        = (__half*)p;         p = align16(p + (size_t)(n + 1) * 2 * 2);   // 0.4MB

    const int B = 256;
    const int NODE8_BLOCKS = cdiv_ll(8LL * n, B);

    // ---- CSR-by-dst via fixed-capacity bucketed sort (no hist/scan) ----
    init_gcur_kernel<<<1, 512, 0, stream>>>(gcur, nbuck);
    partition_kernel<<<cdiv_ll(E, PART_CHUNK), B, 0, stream>>>(src, dst, gcur, bucketed, E, nbuck);
    csr_kernel<<<nbuck, B, 0, stream>>>(bucketed, gcur, x, ends, dinv, sorted_src, xs, n);

    // ---- fused pipeline (8 lanes/node, slice-cooperative gathers) ----
    layer12_kernel<<<NODE8_BLOCKS, B, 0, stream>>>(xs, dinv, sorted_src, ends, W1, b1, W2, h2s, n);
    layer3_kernel<<<NODE8_BLOCKS, B, 0, stream>>>(h2s, dinv, sorted_src, ends, b2, W3, h3s, n);
    layer4_kernel<<<NODE8_BLOCKS, B, 0, stream>>>(h3s, dinv, sorted_src, ends, b3, W4, h4s, n);
    agg2_lsm_kernel<<<NODE8_BLOCKS, B, 0, stream>>>(h4s, dinv, sorted_src, ends, b4, (float*)d_out, n);
}